// Round 18
// baseline (71.813 us; speedup 1.0000x reference)
//
#include <hip/hip_runtime.h>
#include <hip/hip_bf16.h>

typedef __bf16 bf16_t;
typedef bf16_t bf16x8 __attribute__((ext_vector_type(8)));
typedef bf16_t bf16x4 __attribute__((ext_vector_type(4)));
typedef float f32x4 __attribute__((ext_vector_type(4)));

#define MFMA16(a, b, c) __builtin_amdgcn_mfma_f32_16x16x32_bf16((a), (b), (c), 0, 0, 0)

// B=8, T=2048, E=1024, H=128
#define TT 2048
#define EE 1024
#define HH 128
#define UPB 576   // partial slots per batch: sum over 128 16-row qtiles of (qt>>4)+1

// Fragment-major layouts (every consumer load = one coalesced 64x16B instr):
//  Wf: chunk(ct,kt): lane(g,c) elem e = W_{ct>>3}[k=kt*32+g*8+e][n=(ct&7)*16+c]
//  Qf/Kf: chunk(grt,kk): lane(g,c) elem e = M[grt*16+c][kk*32+g*8+e]
//  Vf: chunk(b,vc,hb): lane(g,c) elem j = V[b][vc*32+g*8+j][hb*16+c]

// ---------------- prep: Wf fragment-major, f32 -> bf16 ----------------
__global__ __launch_bounds__(256) void prep_w_kernel(
    const float* __restrict__ Wq, const float* __restrict__ Wk,
    const float* __restrict__ Wv, bf16_t* __restrict__ Wf)
{
    int idx = blockIdx.x * 256 + threadIdx.x;   // 0 .. 393215
    int e  = idx & 7;
    int c  = (idx >> 3) & 15;
    int g  = (idx >> 7) & 3;
    int kt = (idx >> 9) & 31;
    int ct = idx >> 14;                          // 0..23
    int w  = ct >> 3;
    const float* W = (w == 0) ? Wq : (w == 1) ? Wk : Wv;
    int k = kt * 32 + g * 8 + e;
    int n = (ct & 7) * 16 + c;
    Wf[idx] = (bf16_t)W[k * HH + n];
}

// ---------------- fused QKV GEMM: [16384 x 1024] x [1024 x 384] ----------------
// 1024 blocks (4 independent blocks/CU -> 16 waves/CU) x 256 thr (4 waves);
// BM=32, BN=192 (wave 32x48), BK=64 -> 16 phases of 12 MFMA/wave.
// Depth-3 x register pipeline, fragment-major W double-reg-buffered, raw
// s_barrier + lgkmcnt-only, setprio(1) on MFMA cluster.
__global__ __launch_bounds__(256) void qkv_kernel(
    const float* __restrict__ x, const bf16_t* __restrict__ Wf,
    bf16_t* __restrict__ Qf, bf16_t* __restrict__ Kf, bf16_t* __restrict__ Vf)
{
    __shared__ __attribute__((aligned(16))) bf16_t As[2][32][72];  // 144B rows
    const int bx = blockIdx.x;
    const int row0  = (bx & 511) * 32;
    const int nhalf = bx >> 9;                   // pair 512 apart -> same XCD slot
    const int tid  = threadIdx.x;
    const int lane = tid & 63;
    const int wn   = tid >> 6;                    // 4 waves: 48-col slices
    const int g = lane >> 4, c = lane & 15;

    // staging: thread t -> row t>>3 (0..31), 8-f32 colgroup t&7
    const int srow = tid >> 3;
    const int scg  = tid & 7;
    const float* xp = x + (size_t)(row0 + srow) * EE + scg * 8;

    // W fragment base: wave wn covers ct = nhalf*12 + wn*3 .. +2
    const bf16_t* wfb = Wf + ((size_t)(nhalf * 12 + wn * 3) * 32) * 512 + lane * 8;

    f32x4 acc[2][3];
    for (int i = 0; i < 2; ++i)
        for (int j = 0; j < 3; ++j) acc[i][j] = (f32x4)0.0f;

    f32x4 xa[3][2];                               // depth-3 x pipeline
    bf16x8 w[2][6];                               // [set][kk*3+j]

#define BAR() do {                                                            \
    asm volatile("s_waitcnt lgkmcnt(0)" ::: "memory");                        \
    __builtin_amdgcn_s_barrier();                                             \
    __builtin_amdgcn_sched_barrier(0);                                        \
} while (0)
#define XLOAD(S, T) do {                                                      \
    xa[S][0] = *(const f32x4*)(xp + (size_t)(T) * 64);                        \
    xa[S][1] = *(const f32x4*)(xp + (size_t)(T) * 64 + 4);                    \
} while (0)
#define WLOAD(S, T)                                                           \
    for (int kk = 0; kk < 2; ++kk)                                            \
        for (int j = 0; j < 3; ++j)                                           \
            w[S][kk * 3 + j] = *(const bf16x8*)(wfb +                         \
                ((size_t)j * 32 + (T) * 2 + kk) * 512);
#define XWRITE(S, BUF) do {                                                   \
    union { bf16_t h[8]; unsigned long long u[2]; } p_;                       \
    for (int q = 0; q < 4; ++q) {                                             \
        p_.h[q]     = (bf16_t)xa[S][0][q];                                    \
        p_.h[4 + q] = (bf16_t)xa[S][1][q];                                    \
    }                                                                         \
    *reinterpret_cast<unsigned long long*>(&As[BUF][srow][scg * 8])     = p_.u[0]; \
    *reinterpret_cast<unsigned long long*>(&As[BUF][srow][scg * 8 + 4]) = p_.u[1]; \
} while (0)

    // prologue: x tiles 0,1,2 in flight; W frags 0,1; tile0 -> buf0
    XLOAD(0, 0);
    XLOAD(1, 1);
    XLOAD(2, 2);
    WLOAD(0, 0);
    WLOAD(1, 1);
    XWRITE(0, 0);
    BAR();

#pragma unroll
    for (int t = 0; t < 16; ++t) {
        const int buf = t & 1;
        if (t + 3 < 16) XLOAD((t + 3) % 3, t + 3);
        __builtin_amdgcn_s_setprio(1);
        for (int kk = 0; kk < 2; ++kk)
            for (int mt = 0; mt < 2; ++mt) {
                bf16x8 af = *(const bf16x8*)&As[buf][mt * 16 + c][kk * 32 + g * 8];
                for (int j = 0; j < 3; ++j)
                    acc[mt][j] = MFMA16(af, w[t & 1][kk * 3 + j], acc[mt][j]);
            }
        __builtin_amdgcn_s_setprio(0);
        if (t + 2 < 16) WLOAD(t & 1, t + 2);     // refill just-freed W set
        if (t + 1 < 16) XWRITE((t + 1) % 3, buf ^ 1);
        BAR();
    }
#undef XLOAD
#undef WLOAD
#undef XWRITE
#undef BAR

    const float sc = 0.08838834764831845f * 1.4426950408889634f; // 1/sqrt(128)*log2e
    for (int mt = 0; mt < 2; ++mt)
        for (int j = 0; j < 3; ++j) {
            int cb = nhalf * 192 + wn * 48 + j * 16;
            int w_ = cb >> 7;
            int hl = (cb & 127) + c;             // col within Q/K/V
            int t0 = row0 + mt * 16 + g * 4;     // global row
            if (w_ == 2) {
                int b  = t0 >> 11;
                int ttr = t0 & (TT - 1);
                int vc = ttr >> 5, gg = (ttr & 31) >> 3, j0 = ttr & 7;
                int hb = hl >> 4, cc = hl & 15;
                union { bf16_t h4[4]; unsigned long long u; } pk;
                for (int i = 0; i < 4; ++i) pk.h4[i] = (bf16_t)acc[mt][j][i];
                *reinterpret_cast<unsigned long long*>(
                    Vf + ((size_t)((b * 64 + vc) * 8 + hb)) * 512 +
                    (gg * 16 + cc) * 8 + j0) = pk.u;
            } else {
                bf16_t* dst = (w_ == 0) ? Qf : Kf;
                float s = (w_ == 0) ? sc : 1.0f;
                int kk = hl >> 5, gg = (hl & 31) >> 3, e = hl & 7;
                int grt = t0 >> 4;
                for (int i = 0; i < 4; ++i) {
                    int cr = (t0 + i) & 15;
                    dst[((size_t)(grt * 4 + kk)) * 512 + (gg * 16 + cr) * 8 + e] =
                        (bf16_t)(acc[mt][j][i] * s);
                }
            }
        }
}

// ---------------- flash attention: 16-row units, fragment-major I/O ----------------
// unit = (b, 16-row qtile, kvchunk256); one wave per unit, 4 units/block.
// blockIdx&7 = b (XCD-pinned batch). All loads coalesced; no-max exp2 softmax.
__global__ __launch_bounds__(256) void attn_kernel(
    const bf16_t* __restrict__ Qf, const bf16_t* __restrict__ Kf,
    const bf16_t* __restrict__ Vf, bf16_t* __restrict__ Pacc,
    float* __restrict__ Pml)
{
    __shared__ __attribute__((aligned(16))) bf16_t Pl[4][16][40];
    const int tid = threadIdx.x, lane = tid & 63, wid = tid >> 6;
    const int g = lane >> 4, c = lane & 15;
    bf16_t (*P)[40] = Pl[wid];

    const int bx = blockIdx.x;
    const int b  = bx & 7;                       // XCD-pinned batch
    const int u  = 575 - ((bx >> 3) * 4 + wid);  // long-units-first
    int k = 0;
    while (8 * (k + 1) * (k + 2) <= u) ++k;      // tier k = qt>>4, 0..7
    const int r  = u - 8 * k * (k + 1);
    const int qt = 16 * k + r / (k + 1);
    const int ch = r - (r / (k + 1)) * (k + 1);
    const int q0 = qt * 16;
    const int kv_lo = ch * 256;
    int kv_hi = kv_lo + 256; if (kv_hi > q0 + 16) kv_hi = q0 + 16;
    const int sid = b * UPB + 8 * k * (k + 1) + (qt & 15) * (k + 1) + ch;

    bf16x8 qf[4];
    for (int kk = 0; kk < 4; ++kk)
        qf[kk] = *(const bf16x8*)(Qf +
            ((size_t)((b * 128 + qt) * 4 + kk)) * 512 + lane * 8);

    f32x4 acc[8];
    for (int hb = 0; hb < 8; ++hb) acc[hb] = (f32x4)0.0f;
    float ls[4] = {0, 0, 0, 0};

    for (int kv0 = kv_lo; kv0 < kv_hi; kv0 += 32) {
        const int kt = b * 128 + (kv0 >> 4);
        bf16x8 k0f[4], k1f[4], vf[8];
        for (int kk = 0; kk < 4; ++kk) {
            k0f[kk] = *(const bf16x8*)(Kf + ((size_t)(kt * 4 + kk)) * 512 + lane * 8);
            k1f[kk] = *(const bf16x8*)(Kf + ((size_t)((kt + 1) * 4 + kk)) * 512 + lane * 8);
        }
        const int vcb = (b * 64 + (kv0 >> 5)) * 8;
        for (int hb = 0; hb < 8; ++hb)
            vf[hb] = *(const bf16x8*)(Vf + ((size_t)(vcb + hb)) * 512 + lane * 8);

        f32x4 s0 = (f32x4)0.0f, s1 = (f32x4)0.0f;
        for (int kk = 0; kk < 4; ++kk) {
            s0 = MFMA16(qf[kk], k0f[kk], s0);
            s1 = MFMA16(qf[kk], k1f[kk], s1);
        }
        if (kv0 + 32 > q0) {                     // diagonal tiles: causal mask
            for (int i = 0; i < 4; ++i) {
                int row = q0 + g * 4 + i;
                if (kv0 + c > row)      s0[i] = -1e30f;
                if (kv0 + 16 + c > row) s1[i] = -1e30f;
            }
        }
        float p0[4], p1[4];
        for (int i = 0; i < 4; ++i) {            // p = 2^s (log2e folded into Q)
            p0[i] = exp2f(s0[i]);
            p1[i] = exp2f(s1[i]);
            ls[i] += p0[i] + p1[i];
        }
        for (int i = 0; i < 4; ++i) {
            P[g * 4 + i][c]      = (bf16_t)p0[i];
            P[g * 4 + i][c + 16] = (bf16_t)p1[i];
        }
        __builtin_amdgcn_wave_barrier();
        asm volatile("s_waitcnt lgkmcnt(0)" ::: "memory");
        __builtin_amdgcn_sched_barrier(0);
        bf16x8 pa = *(const bf16x8*)&P[c][g * 8];
        __builtin_amdgcn_s_setprio(1);
        for (int hb = 0; hb < 8; ++hb)
            acc[hb] = MFMA16(pa, vf[hb], acc[hb]);
        __builtin_amdgcn_s_setprio(0);
        __builtin_amdgcn_wave_barrier();
    }

    for (int off = 1; off < 16; off <<= 1)
        for (int i = 0; i < 4; ++i) ls[i] += __shfl_xor(ls[i], off, 64);
    if (c == 0)
        for (int i = 0; i < 4; ++i)
            Pml[(size_t)sid * 16 + g * 4 + i] = ls[i];

    // Pacc transposed: po[col=128][row=16]; packed 8B stores
    bf16_t* po = Pacc + (size_t)sid * (16 * 128);
    for (int hb = 0; hb < 8; ++hb) {
        union { bf16_t h4[4]; unsigned long long u; } pk;
        for (int i = 0; i < 4; ++i) pk.h4[i] = (bf16_t)acc[hb][i];
        *reinterpret_cast<unsigned long long*>(
            po + (hb * 16 + c) * 16 + g * 4) = pk.u;
    }
}

// ---------------- combine partials (plain sums; Pacc is [col][row=16]) ----------------
__global__ __launch_bounds__(128) void combine_kernel(
    const bf16_t* __restrict__ Pacc, const float* __restrict__ Pml,
    float* __restrict__ out)
{
    __shared__ float invL[8];
    const int qt = blockIdx.x;                   // 0..127
    const int b  = blockIdx.y;
    const int qz = blockIdx.z;                   // row-half 0..1
    const int k  = qt >> 4;
    const int base  = b * UPB + 8 * k * (k + 1) + (qt & 15) * (k + 1);
    const int count = k + 1;
    const int tid = threadIdx.x;                 // = col 0..127

    if (tid < 8) {
        float L = 0.0f;
        for (int cu = 0; cu < count; ++cu)
            L += Pml[(size_t)(base + cu) * 16 + qz * 8 + tid];
        invL[tid] = 1.0f / L;
    }
    __syncthreads();

    float s[8];
    for (int r = 0; r < 8; ++r) s[r] = 0.0f;
    for (int cu = 0; cu < count; ++cu) {
        bf16x8 v = *(const bf16x8*)(
            Pacc + (size_t)(base + cu) * 2048 + tid * 16 + qz * 8);
        for (int j = 0; j < 8; ++j) s[j] += (float)v[j];
    }
    const int q0 = qt * 16 + qz * 8;
    for (int r = 0; r < 8; ++r)
        out[((size_t)b * TT + q0 + r) * HH + tid] = s[r] * invL[r];
}

extern "C" void kernel_launch(void* const* d_in, const int* in_sizes, int n_in,
                              void* d_out, int out_size, void* d_ws, size_t ws_size,
                              hipStream_t stream)
{
    const float* x  = (const float*)d_in[0];
    const float* Wq = (const float*)d_in[1];
    const float* Wk = (const float*)d_in[2];
    const float* Wv = (const float*)d_in[3];

    char* ws = (char*)d_ws;
    bf16_t* Wf   = (bf16_t*)ws;                       // 768 KB fragment-major
    bf16_t* Qf   = (bf16_t*)(ws + (1u  << 20));       // 4 MB fragment-major
    bf16_t* Kf   = (bf16_t*)(ws + (5u  << 20));       // 4 MB fragment-major
    bf16_t* Vf   = (bf16_t*)(ws + (9u  << 20));       // 4 MB fragment-major
    bf16_t* Pacc = (bf16_t*)(ws + (13u << 20));       // 4608*2048*2 B = 18.9 MB
    float*  Pml  = (float*) (ws + (32u << 20));       // 4608*64 B

    prep_w_kernel<<<1536, 256, 0, stream>>>(Wq, Wk, Wv, Wf);
    qkv_kernel<<<1024, 256, 0, stream>>>(x, Wf, Qf, Kf, Vf);
    attn_kernel<<<1152, 256, 0, stream>>>(Qf, Kf, Vf, Pacc, Pml);
    combine_kernel<<<dim3(128, 8, 2), 128, 0, stream>>>(Pacc, Pml, (float*)d_out);
}

// Round 21
// 65.091 us; speedup vs baseline: 1.1033x; 1.1033x over previous
//
#include <hip/hip_runtime.h>
#include <hip/hip_bf16.h>

typedef __bf16 bf16_t;
typedef bf16_t bf16x8 __attribute__((ext_vector_type(8)));
typedef bf16_t bf16x4 __attribute__((ext_vector_type(4)));
typedef float f32x4 __attribute__((ext_vector_type(4)));

#define MFMA16(a, b, c) __builtin_amdgcn_mfma_f32_16x16x32_bf16((a), (b), (c), 0, 0, 0)

// B=8, T=2048, E=1024, H=128
#define TT 2048
#define EE 1024
#define HH 128
#define UPB 576   // partial slots per batch: sum over 128 16-row qtiles of (qt>>4)+1

typedef __attribute__((address_space(3))) void lds_void_t;
typedef const __attribute__((address_space(1))) void gbl_void_t;

// Fragment-major layouts (every consumer load = one coalesced 64x16B instr):
//  Wf: chunk(ct,kt): lane(g,c) elem e = W_{ct>>3}[k=kt*32+g*8+e][n=(ct&7)*16+c]
//  Qf/Kf: chunk(grt,kk): lane(g,c) elem e = M[grt*16+c][kk*32+g*8+e]
//  Vf: chunk(b,vc,hb): lane(g,c) elem j = V[b][vc*32+g*8+j][hb*16+c]

// ---------------- prep: Wf fragment-major, f32 -> bf16 ----------------
__global__ __launch_bounds__(256) void prep_w_kernel(
    const float* __restrict__ Wq, const float* __restrict__ Wk,
    const float* __restrict__ Wv, bf16_t* __restrict__ Wf)
{
    int idx = blockIdx.x * 256 + threadIdx.x;   // 0 .. 393215
    int e  = idx & 7;
    int c  = (idx >> 3) & 15;
    int g  = (idx >> 7) & 3;
    int kt = (idx >> 9) & 31;
    int ct = idx >> 14;                          // 0..23
    int w  = ct >> 3;
    const float* W = (w == 0) ? Wq : (w == 1) ? Wk : Wv;
    int k = kt * 32 + g * 8 + e;
    int n = (ct & 7) * 16 + c;
    Wf[idx] = (bf16_t)W[k * HH + n];
}

// ---------------- fused QKV GEMM: [16384 x 1024] x [1024 x 384] ----------------
// 512 blocks (2/CU, nhalf pairs co-XCD) x 256 thr (4 waves, wave 64x48);
// BM=64, BN=192, BK=64. A staged f32 via global_load_lds(16B): wave-uniform
// LDS dest + inverse-XOR-swizzled global source + swizzled ds_read.
// COUNTED vmcnt: ops newer than STAGE(t) = W(t+1)[6] + S(t+1)[4] = 10, so
// vmcnt(10) exactly drains S(t) while keeping the next stage in flight.
__global__ __launch_bounds__(256) void qkv_kernel(
    const float* __restrict__ x, const bf16_t* __restrict__ Wf,
    bf16_t* __restrict__ Qf, bf16_t* __restrict__ Kf, bf16_t* __restrict__ Vf)
{
    __shared__ __attribute__((aligned(16))) float As[2][64][64];  // 2 x 16 KB
    const int bx = blockIdx.x;
    const int row0  = (bx & 255) * 64;
    const int nhalf = bx >> 8;                   // bx, bx+256: same XCD, share x
    const int tid  = threadIdx.x;
    const int lane = tid & 63;
    const int wid  = tid >> 6;                    // 4 waves: 48-col slices
    const int g = lane >> 4, c = lane & 15;

    // W fragment base: wave wid covers ct = nhalf*12 + wid*3 .. +2
    const bf16_t* wfb = Wf + ((size_t)(nhalf * 12 + wid * 3) * 32) * 512 + lane * 8;

    f32x4 acc[4][3];
    for (int i = 0; i < 4; ++i)
        for (int j = 0; j < 3; ++j) acc[i][j] = (f32x4)0.0f;

    bf16x8 w[2][6];                               // [set][kk*3+j]

    // stage: wave wid covers rows wid*16..wid*16+15; 4 issues x (4 rows x 64 f32).
    // LDS dest wave-uniform (HW: lane l -> base + l*16 = row + (l>>4), slot l&15);
    // global source col-slot XOR-swizzled by row&7 (inverse of read swizzle).
#define STAGE(BUF, T)                                                         \
    for (int i = 0; i < 4; ++i) {                                             \
        int srow = wid * 16 + i * 4 + (lane >> 4);                            \
        int scol = (lane & 15) ^ (srow & 7);                                  \
        __builtin_amdgcn_global_load_lds(                                     \
            (gbl_void_t*)(x + (size_t)(row0 + srow) * EE + (size_t)(T) * 64 + scol * 4), \
            (lds_void_t*)&As[BUF][wid * 16 + i * 4][0],                       \
            16, 0, 0);                                                        \
    }
#define WLOAD(S, T)                                                           \
    for (int kk = 0; kk < 2; ++kk)                                            \
        for (int j = 0; j < 3; ++j)                                           \
            w[S][kk * 3 + j] = *(const bf16x8*)(wfb +                         \
                ((size_t)j * 32 + (T) * 2 + kk) * 512);
    // read frag (row = mt*16+c, 16B slots s0,s0+1 each XOR c&7) + cvt + MFMA
#define COMPUTE(BUF, S) do {                                                  \
    for (int kk = 0; kk < 2; ++kk)                                            \
        for (int mt = 0; mt < 4; ++mt) {                                      \
            const char* rb = (const char*)&As[BUF][mt * 16 + c][0];           \
            int s0 = kk * 8 + g * 2;                                          \
            f32x4 r0 = *(const f32x4*)(rb + ((s0 ^ (c & 7)) << 4));           \
            f32x4 r1 = *(const f32x4*)(rb + (((s0 + 1) ^ (c & 7)) << 4));     \
            union { bf16_t h[8]; bf16x8 v; } u_;                              \
            for (int q = 0; q < 4; ++q) {                                     \
                u_.h[q]     = (bf16_t)r0[q];                                  \
                u_.h[4 + q] = (bf16_t)r1[q];                                  \
            }                                                                 \
            for (int j = 0; j < 3; ++j)                                       \
                acc[mt][j] = MFMA16(u_.v, w[S][kk * 3 + j], acc[mt][j]);      \
        } } while (0)

    // prologue: W(0), W(1), S(0); drain once
    WLOAD(0, 0);
    WLOAD(1, 1);
    STAGE(0, 0);
    asm volatile("s_waitcnt vmcnt(0)" ::: "memory");
    __builtin_amdgcn_s_barrier();
    __builtin_amdgcn_sched_barrier(0);

#pragma unroll
    for (int t = 0; t < 16; ++t) {
        const int buf = t & 1;
        if (t + 1 < 16) STAGE(buf ^ 1, t + 1);   // 4 loads for tile t+1
        // counted wait: newer-than-S(t) = W(t+1)[6] + S(t+1)[4] = 10
        if (t < 14)      asm volatile("s_waitcnt vmcnt(10)" ::: "memory");
        else if (t < 15) asm volatile("s_waitcnt vmcnt(4)"  ::: "memory");
        else             asm volatile("s_waitcnt vmcnt(0)"  ::: "memory");
        __builtin_amdgcn_s_barrier();
        __builtin_amdgcn_sched_barrier(0);
        __builtin_amdgcn_s_setprio(1);
        COMPUTE(buf, buf);
        __builtin_amdgcn_s_setprio(0);
        if (t + 2 < 16) WLOAD(buf, t + 2);       // refill just-freed W set
        asm volatile("s_waitcnt lgkmcnt(0)" ::: "memory");
        __builtin_amdgcn_s_barrier();
        __builtin_amdgcn_sched_barrier(0);
    }
#undef STAGE
#undef WLOAD
#undef COMPUTE

    const float sc = 0.08838834764831845f * 1.4426950408889634f; // 1/sqrt(128)*log2e
    for (int mt = 0; mt < 4; ++mt)
        for (int j = 0; j < 3; ++j) {
            int cb = nhalf * 192 + wid * 48 + j * 16;
            int w_ = cb >> 7;
            int hl = (cb & 127) + c;             // col within Q/K/V
            int t0 = row0 + mt * 16 + g * 4;     // global row
            if (w_ == 2) {
                int b  = t0 >> 11;
                int ttr = t0 & (TT - 1);
                int vc = ttr >> 5, gg = (ttr & 31) >> 3, j0 = ttr & 7;
                int hb = hl >> 4, cc = hl & 15;
                union { bf16_t h4[4]; unsigned long long u; } pk;
                for (int i = 0; i < 4; ++i) pk.h4[i] = (bf16_t)acc[mt][j][i];
                *reinterpret_cast<unsigned long long*>(
                    Vf + ((size_t)((b * 64 + vc) * 8 + hb)) * 512 +
                    (gg * 16 + cc) * 8 + j0) = pk.u;
            } else {
                bf16_t* dst = (w_ == 0) ? Qf : Kf;
                float s = (w_ == 0) ? sc : 1.0f;
                int kk = hl >> 5, gg = (hl & 31) >> 3, e = hl & 7;
                int grt = t0 >> 4;
                for (int i = 0; i < 4; ++i) {
                    int cr = (t0 + i) & 15;
                    dst[((size_t)(grt * 4 + kk)) * 512 + (gg * 16 + cr) * 8 + e] =
                        (bf16_t)(acc[mt][j][i] * s);
                }
            }
        }
}

// ---------------- flash attention: 16-row units, fragment-major I/O ----------------
// unit = (b, 16-row qtile, kvchunk256); one wave per unit, 4 units/block.
// blockIdx&7 = b (XCD-pinned batch). All loads coalesced; no-max exp2 softmax.
__global__ __launch_bounds__(256) void attn_kernel(
    const bf16_t* __restrict__ Qf, const bf16_t* __restrict__ Kf,
    const bf16_t* __restrict__ Vf, bf16_t* __restrict__ Pacc,
    float* __restrict__ Pml)
{
    __shared__ __attribute__((aligned(16))) bf16_t Pl[4][16][40];
    const int tid = threadIdx.x, lane = tid & 63, wid = tid >> 6;
    const int g = lane >> 4, c = lane & 15;
    bf16_t (*P)[40] = Pl[wid];

    const int bx = blockIdx.x;
    const int b  = bx & 7;                       // XCD-pinned batch
    const int u  = 575 - ((bx >> 3) * 4 + wid);  // long-units-first
    int k = 0;
    while (8 * (k + 1) * (k + 2) <= u) ++k;      // tier k = qt>>4, 0..7
    const int r  = u - 8 * k * (k + 1);
    const int qt = 16 * k + r / (k + 1);
    const int ch = r - (r / (k + 1)) * (k + 1);
    const int q0 = qt * 16;
    const int kv_lo = ch * 256;
    int kv_hi = kv_lo + 256; if (kv_hi > q0 + 16) kv_hi = q0 + 16;
    const int sid = b * UPB + 8 * k * (k + 1) + (qt & 15) * (k + 1) + ch;

    bf16x8 qf[4];
    for (int kk = 0; kk < 4; ++kk)
        qf[kk] = *(const bf16x8*)(Qf +
            ((size_t)((b * 128 + qt) * 4 + kk)) * 512 + lane * 8);

    f32x4 acc[8];
    for (int hb = 0; hb < 8; ++hb) acc[hb] = (f32x4)0.0f;
    float ls[4] = {0, 0, 0, 0};

    for (int kv0 = kv_lo; kv0 < kv_hi; kv0 += 32) {
        const int kt = b * 128 + (kv0 >> 4);
        bf16x8 k0f[4], k1f[4], vf[8];
        for (int kk = 0; kk < 4; ++kk) {
            k0f[kk] = *(const bf16x8*)(Kf + ((size_t)(kt * 4 + kk)) * 512 + lane * 8);
            k1f[kk] = *(const bf16x8*)(Kf + ((size_t)((kt + 1) * 4 + kk)) * 512 + lane * 8);
        }
        const int vcb = (b * 64 + (kv0 >> 5)) * 8;
        for (int hb = 0; hb < 8; ++hb)
            vf[hb] = *(const bf16x8*)(Vf + ((size_t)(vcb + hb)) * 512 + lane * 8);

        f32x4 s0 = (f32x4)0.0f, s1 = (f32x4)0.0f;
        for (int kk = 0; kk < 4; ++kk) {
            s0 = MFMA16(qf[kk], k0f[kk], s0);
            s1 = MFMA16(qf[kk], k1f[kk], s1);
        }
        if (kv0 + 32 > q0) {                     // diagonal tiles: causal mask
            for (int i = 0; i < 4; ++i) {
                int row = q0 + g * 4 + i;
                if (kv0 + c > row)      s0[i] = -1e30f;
                if (kv0 + 16 + c > row) s1[i] = -1e30f;
            }
        }
        float p0[4], p1[4];
        for (int i = 0; i < 4; ++i) {            // p = 2^s (log2e folded into Q)
            p0[i] = exp2f(s0[i]);
            p1[i] = exp2f(s1[i]);
            ls[i] += p0[i] + p1[i];
        }
        for (int i = 0; i < 4; ++i) {
            P[g * 4 + i][c]      = (bf16_t)p0[i];
            P[g * 4 + i][c + 16] = (bf16_t)p1[i];
        }
        __builtin_amdgcn_wave_barrier();
        asm volatile("s_waitcnt lgkmcnt(0)" ::: "memory");
        __builtin_amdgcn_sched_barrier(0);
        bf16x8 pa = *(const bf16x8*)&P[c][g * 8];
        __builtin_amdgcn_s_setprio(1);
        for (int hb = 0; hb < 8; ++hb)
            acc[hb] = MFMA16(pa, vf[hb], acc[hb]);
        __builtin_amdgcn_s_setprio(0);
        __builtin_amdgcn_wave_barrier();
    }

    for (int off = 1; off < 16; off <<= 1)
        for (int i = 0; i < 4; ++i) ls[i] += __shfl_xor(ls[i], off, 64);
    if (c == 0)
        for (int i = 0; i < 4; ++i)
            Pml[(size_t)sid * 16 + g * 4 + i] = ls[i];

    // Pacc transposed: po[col=128][row=16]; packed 8B stores
    bf16_t* po = Pacc + (size_t)sid * (16 * 128);
    for (int hb = 0; hb < 8; ++hb) {
        union { bf16_t h4[4]; unsigned long long u; } pk;
        for (int i = 0; i < 4; ++i) pk.h4[i] = (bf16_t)acc[hb][i];
        *reinterpret_cast<unsigned long long*>(
            po + (hb * 16 + c) * 16 + g * 4) = pk.u;
    }
}

// ---------------- combine partials (plain sums; Pacc is [col][row=16]) ----------------
__global__ __launch_bounds__(128) void combine_kernel(
    const bf16_t* __restrict__ Pacc, const float* __restrict__ Pml,
    float* __restrict__ out)
{
    __shared__ float invL[8];
    const int qt = blockIdx.x;                   // 0..127
    const int b  = blockIdx.y;
    const int qz = blockIdx.z;                   // row-half 0..1
    const int k  = qt >> 4;
    const int base  = b * UPB + 8 * k * (k + 1) + (qt & 15) * (k + 1);
    const int count = k + 1;
    const int tid = threadIdx.x;                 // = col 0..127

    if (tid < 8) {
        float L = 0.0f;
        for (int cu = 0; cu < count; ++cu)
            L += Pml[(size_t)(base + cu) * 16 + qz * 8 + tid];
        invL[tid] = 1.0f / L;
    }
    __syncthreads();

    float s[8];
    for (int r = 0; r < 8; ++r) s[r] = 0.0f;
    for (int cu = 0; cu < count; ++cu) {
        bf16x8 v = *(const bf16x8*)(
            Pacc + (size_t)(base + cu) * 2048 + tid * 16 + qz * 8);
        for (int j = 0; j < 8; ++j) s[j] += (float)v[j];
    }
    const int q0 = qt * 16 + qz * 8;
    for (int r = 0; r < 8; ++r)
        out[((size_t)b * TT + q0 + r) * HH + tid] = s[r] * invL[r];
}

extern "C" void kernel_launch(void* const* d_in, const int* in_sizes, int n_in,
                              void* d_out, int out_size, void* d_ws, size_t ws_size,
                              hipStream_t stream)
{
    const float* x  = (const float*)d_in[0];
    const float* Wq = (const float*)d_in[1];
    const float* Wk = (const float*)d_in[2];
    const float* Wv = (const float*)d_in[3];

    char* ws = (char*)d_ws;
    bf16_t* Wf   = (bf16_t*)ws;                       // 768 KB fragment-major
    bf16_t* Qf   = (bf16_t*)(ws + (1u  << 20));       // 4 MB fragment-major
    bf16_t* Kf   = (bf16_t*)(ws + (5u  << 20));       // 4 MB fragment-major
    bf16_t* Vf   = (bf16_t*)(ws + (9u  << 20));       // 4 MB fragment-major
    bf16_t* Pacc = (bf16_t*)(ws + (13u << 20));       // 4608*2048*2 B = 18.9 MB
    float*  Pml  = (float*) (ws + (32u << 20));       // 4608*64 B

    prep_w_kernel<<<1536, 256, 0, stream>>>(Wq, Wk, Wv, Wf);
    qkv_kernel<<<512, 256, 0, stream>>>(x, Wf, Qf, Kf, Vf);
    attn_kernel<<<1152, 256, 0, stream>>>(Qf, Kf, Vf, Pacc, Pml);
    combine_kernel<<<dim3(128, 8, 2), 128, 0, stream>>>(Pacc, Pml, (float*)d_out);
}